// Round 10
// baseline (221.399 us; speedup 1.0000x reference)
//
#include <hip/hip_runtime.h>
#include <hip/hip_bf16.h>

// Sizes (fixed): b=2, n=1024, dim=512, h=8, L=8, dh=64
// exp(-d2/T) with T=0.1 -> exp2(C*d2), C = -10*log2(e)
#define CEXP (-14.4269504088896340736f)

typedef __attribute__((ext_vector_type(8))) short bfrag8;   // 8 bf16 (4 VGPR) MFMA operand
typedef __attribute__((ext_vector_type(4))) float fvec4;    // MFMA accumulator
typedef __attribute__((ext_vector_type(4))) unsigned uint4v;

__device__ inline unsigned short f2bf(float f) {            // RNE float->bf16
    unsigned u = __builtin_bit_cast(unsigned, f);
    u += 0x7fffu + ((u >> 16) & 1u);
    return (unsigned short)(u >> 16);
}
__device__ inline float bf2f(unsigned short h) {
    unsigned u = ((unsigned)h) << 16;
    return __builtin_bit_cast(float, u);
}

// Wave64 sum via DPP (rocPRIM pattern). ctrl/rmask immediates via template params.
template <int CTRL, int RMASK>
__device__ __forceinline__ float dpp_add(float v) {
    int m = __builtin_amdgcn_update_dpp(0, __builtin_bit_cast(int, v), CTRL, RMASK, 0xf, true);
    return v + __builtin_bit_cast(float, m);
}
__device__ __forceinline__ float wave_sum64(float v) {
    v = dpp_add<0xB1,  0xf>(v);   // quad_perm(1,0,3,2)
    v = dpp_add<0x4E,  0xf>(v);   // quad_perm(2,3,0,1)
    v = dpp_add<0x141, 0xf>(v);   // row_half_mirror
    v = dpp_add<0x140, 0xf>(v);   // row_mirror
    v = dpp_add<0x142, 0xa>(v);   // row_bcast15 into rows 1,3
    v = dpp_add<0x143, 0xc>(v);   // row_bcast31 into rows 2,3
    return __builtin_bit_cast(float, __builtin_amdgcn_readlane(__builtin_bit_cast(int, v), 63));
}

// ---------------- K_B: Wqp/Wkp = Wq/Wk projected on normalized theta; extract Wv ----
__global__ __launch_bounds__(256) void k_wproj(const float* __restrict__ Wqkv,
                                               const float* __restrict__ theta,
                                               float* __restrict__ Wqp,
                                               float* __restrict__ Wkp,
                                               float* __restrict__ Wv) {
    __shared__ float th_s[64 * 65];
    int tid = threadIdx.x;
    int hl = tid & 63, cl = tid >> 6;
    #pragma unroll
    for (int i = 0; i < 16; ++i) {
        int r = cl * 16 + i;
        th_s[r * 65 + hl] = theta[r * 64 + hl];
    }
    __syncthreads();
    const float* ts = th_s + hl * 65;
    float ss = 0.f;
    #pragma unroll 8
    for (int d = 0; d < 64; ++d) ss = fmaf(ts[d], ts[d], ss);
    float inv = rsqrtf(ss);
    int c = blockIdx.x * 4 + cl;
    int h = hl >> 3;
    const float* wq = Wqkv + c * 1536 + h * 64;
    const float* wk = wq + 512;
    float aq = 0.f, ak = 0.f;
    #pragma unroll 4
    for (int d = 0; d < 64; ++d) {
        float tv = ts[d];
        aq = fmaf(wq[d], tv, aq);
        ak = fmaf(wk[d], tv, ak);
    }
    Wqp[c * 64 + hl] = aq * inv;
    Wkp[c * 64 + hl] = ak * inv;

    int c0 = blockIdx.x * 4;
    const float4* src = (const float4*)(Wqkv + 1024);
    float4* dst = (float4*)Wv;
    #pragma unroll
    for (int j = 0; j < 2; ++j) {
        int idx = j * 256 + tid;
        int cr = c0 + (idx >> 7), o4 = idx & 127;
        dst[cr * 128 + o4] = src[cr * 384 + o4];
    }
}

// ---------------- K_C: qp/kp = scale * x @ W{q,k}p, layout [bh][l][n] ----------------
__global__ __launch_bounds__(256) void k_qkp(const float* __restrict__ x,
                                             const float* __restrict__ Wqp,
                                             const float* __restrict__ Wkp,
                                             float* __restrict__ qp,
                                             float* __restrict__ kp) {
    __shared__ float xs[4 * 512];
    int tid = threadIdx.x;
    int i0 = blockIdx.x * 4;                 // 512 blocks
    const float4* xg = (const float4*)(x + i0 * 512);
    float4* xs4 = (float4*)xs;
    #pragma unroll
    for (int j = 0; j < 2; ++j) xs4[j * 256 + tid] = xg[j * 256 + tid];
    __syncthreads();

    int t  = tid & 127;
    int rg = tid >> 7;
    int hl = t & 63;
    const float* Bm = (t & 64) ? Wkp : Wqp;
    const float* xr = xs + rg * 2 * 512;
    float a[2] = {0.f, 0.f};
    for (int c4 = 0; c4 < 128; ++c4) {
        float b0 = Bm[(c4 * 4 + 0) * 64 + hl];
        float b1 = Bm[(c4 * 4 + 1) * 64 + hl];
        float b2 = Bm[(c4 * 4 + 2) * 64 + hl];
        float b3 = Bm[(c4 * 4 + 3) * 64 + hl];
        #pragma unroll
        for (int r = 0; r < 2; ++r) {
            float4 xv = *(const float4*)(xr + r * 512 + c4 * 4);
            a[r] = fmaf(xv.x, b0, fmaf(xv.y, b1, fmaf(xv.z, b2, fmaf(xv.w, b3, a[r]))));
        }
    }
    int h = hl >> 3, l = hl & 7;
    float* dst = (t & 64) ? kp : qp;
    #pragma unroll
    for (int r = 0; r < 2; ++r) {
        int row = i0 + rg * 2 + r;
        int b = row >> 10, i = row & 1023;
        dst[((b * 8 + h) * 8 + l) * 1024 + i] = a[r] * 0.125f;
    }
}

// ---------------- K_D1: vnat = x @ Wv, natural layout; 512 thr, 1 col x 8 rows ----------
__global__ __launch_bounds__(512) void k_vproj_nat(const float* __restrict__ x,
                                                   const float* __restrict__ Wv,
                                                   float* __restrict__ vnat) {
    __shared__ float xs[8 * 512];
    int tid = threadIdx.x;
    int i0 = blockIdx.x * 8;                 // 256 blocks
    const float4* xg = (const float4*)(x + i0 * 512);
    float4* xs4 = (float4*)xs;
    #pragma unroll
    for (int j = 0; j < 2; ++j) xs4[j * 512 + tid] = xg[j * 512 + tid];
    __syncthreads();

    int col = tid;
    float a[8];
    #pragma unroll
    for (int r = 0; r < 8; ++r) a[r] = 0.f;
    const float* wp = Wv + col;
    for (int c4 = 0; c4 < 128; ++c4) {
        float w0 = wp[(c4 * 4 + 0) * 512];
        float w1 = wp[(c4 * 4 + 1) * 512];
        float w2 = wp[(c4 * 4 + 2) * 512];
        float w3 = wp[(c4 * 4 + 3) * 512];
        #pragma unroll
        for (int r = 0; r < 8; ++r) {
            float4 xv = *(const float4*)(xs + r * 512 + c4 * 4);
            a[r] = fmaf(xv.x, w0, fmaf(xv.y, w1, fmaf(xv.z, w2, fmaf(xv.w, w3, a[r]))));
        }
    }
    #pragma unroll
    for (int r = 0; r < 8; ++r) vnat[(i0 + r) * 512 + col] = a[r];
}

// ---------------- K_D2: vT = transpose(vnat) as bf16 hi/lo, [bh][d][n] ----------------
__global__ __launch_bounds__(256) void k_vT(const float* __restrict__ vnat,
                                            unsigned short* __restrict__ vThi,
                                            unsigned short* __restrict__ vTlo) {
    __shared__ float ts[64 * 65];
    int blk = blockIdx.x;                    // 256 = 16 bh * 16 row-tiles
    int bh = blk >> 4;
    int i0 = (blk & 15) * 64;
    int b = bh >> 3, h = bh & 7;
    int tid = threadIdx.x;
    int col = tid & 63, r0 = tid >> 6;
    const float* src = vnat + (size_t)(b * 1024 + i0) * 512 + h * 64;
    #pragma unroll
    for (int k = 0; k < 16; ++k) {
        int r = r0 + 4 * k;
        ts[r * 65 + col] = src[r * 512 + col];
    }
    __syncthreads();
    int i = tid & 63, d0 = tid >> 6;
    size_t base = (size_t)bh * 65536 + i0 + i;
    #pragma unroll
    for (int k = 0; k < 16; ++k) {
        int d = d0 + 4 * k;
        float val = ts[i * 65 + d];
        unsigned short hi = f2bf(val);
        vThi[base + (size_t)d * 1024] = hi;
        vTlo[base + (size_t)d * 1024] = f2bf(val - bf2f(hi));
    }
}

// ---------------- K_E1: softmax-average rows -> packed (lo<<16|hi) u32 into attn buf ----
// 512 thr / 8 waves; wave w owns row rowbase+w. No P-stash, one barrier, b128 LDS reads.
__global__ __launch_bounds__(512) void k_attn(const float* __restrict__ qp,
                                              const float* __restrict__ kp,
                                              unsigned* __restrict__ attnp) {
    __shared__ float s_buf[8 * 1024];        // kp staging, 32 KB
    int bx = blockIdx.x;                     // 2048
    int bh = bx >> 7;
    int rowbase = (bx & 127) * 8;
    int tid = threadIdx.x;
    int w = tid >> 6, lane = tid & 63;

    const float4* kp4 = (const float4*)(kp + bh * 8192);
    float4* kps4 = (float4*)s_buf;
    #pragma unroll
    for (int k = 0; k < 4; ++k) kps4[k * 512 + tid] = kp4[k * 512 + tid];

    int r = rowbase + w;
    float qv[8];
    #pragma unroll
    for (int l = 0; l < 8; ++l) qv[l] = qp[bh * 8192 + l * 1024 + r];
    __syncthreads();

    float acc[16];                           // col = mm*256 + lane*4 + j  (m = mm*4+j)
    #pragma unroll
    for (int m = 0; m < 16; ++m) acc[m] = 0.f;

    for (int l = 0; l < 8; ++l) {
        float4 kv4[4];
        #pragma unroll
        for (int mm = 0; mm < 4; ++mm)
            kv4[mm] = *(const float4*)(s_buf + l * 1024 + mm * 256 + lane * 4);
        float sq = -2.f * CEXP * qv[l];
        float e[16];
        #pragma unroll
        for (int mm = 0; mm < 4; ++mm) {
            #pragma unroll
            for (int j = 0; j < 4; ++j) {
                float kvv = kv4[mm][j];
                e[mm * 4 + j] = __builtin_amdgcn_exp2f(fmaf(sq, kvv, CEXP * kvv * kvv));
            }
        }
        float s = (((e[0]+e[1])+(e[2]+e[3])) + ((e[4]+e[5])+(e[6]+e[7])))
                + (((e[8]+e[9])+(e[10]+e[11])) + ((e[12]+e[13])+(e[14]+e[15])));
        float inv = 0.125f * __builtin_amdgcn_rcpf(wave_sum64(s));
        #pragma unroll
        for (int m = 0; m < 16; ++m) acc[m] = fmaf(e[m], inv, acc[m]);
    }

    // store packed hi/lo u32, 16B coalesced
    unsigned* aR = attnp + ((size_t)(bh * 1024 + r)) * 1024;
    #pragma unroll
    for (int mm = 0; mm < 4; ++mm) {
        uint4v pk;
        #pragma unroll
        for (int j = 0; j < 4; ++j) {
            float v = acc[mm * 4 + j];
            unsigned short hi = f2bf(v);
            unsigned short lo = f2bf(v - bf2f(hi));
            pk[j] = ((unsigned)lo << 16) | hi;
        }
        *(uint4v*)(aR + mm * 256 + lane * 4) = pk;
    }
}

// ---------------- K_E2: oh = P @ v (MFMA, packed-A); rewrite attn as f32 in place ------
// 512 blocks = 16 bh x 32 row-groups(32 rows). 256 thr / 4 waves; wave = 16 cols x 4 rt.
__global__ __launch_bounds__(256) void k_pv(const unsigned* __restrict__ attnp,
                                            const unsigned short* __restrict__ vThi,
                                            const unsigned short* __restrict__ vTlo,
                                            float* __restrict__ attnf,
                                            float* __restrict__ oh) {
    int blk = blockIdx.x;
    int bh = blk >> 5, rg = blk & 31;
    int tid = threadIdx.x;
    int w = tid >> 6, lane = tid & 63;
    int ar = lane & 15;                      // A row (0-7 hi, 8-15 lo) / B col
    int ak = (lane >> 4) * 8;                // k sub-chunk
    unsigned psel = (ar < 8) ? 0x05040100u : 0x07060302u;   // low/high halves

    const unsigned* Ab[4];
    #pragma unroll
    for (int t = 0; t < 4; ++t) {
        int row = rg * 32 + t * 8 + (ar & 7);
        Ab[t] = attnp + ((size_t)(bh * 1024 + row)) * 1024 + ak;
    }
    size_t boff = (size_t)bh * 65536 + (size_t)(w * 16 + ar) * 1024 + ak;
    const unsigned short* bhp = vThi + boff;
    const unsigned short* blp = vTlo + boff;

    fvec4 acc[4];
    #pragma unroll
    for (int t = 0; t < 4; ++t) acc[t] = (fvec4){0.f, 0.f, 0.f, 0.f};

    #pragma unroll 2
    for (int s = 0; s < 32; ++s) {
        bfrag8 vh = *(const bfrag8*)(bhp + s * 32);
        bfrag8 vl = *(const bfrag8*)(blp + s * 32);
        #pragma unroll
        for (int t = 0; t < 4; ++t) {
            uint4v a0 = *(const uint4v*)(Ab[t] + s * 32);
            uint4v a1 = *(const uint4v*)(Ab[t] + s * 32 + 4);
            uint4v fr;
            fr[0] = __builtin_amdgcn_perm(a0[1], a0[0], psel);
            fr[1] = __builtin_amdgcn_perm(a0[3], a0[2], psel);
            fr[2] = __builtin_amdgcn_perm(a1[1], a1[0], psel);
            fr[3] = __builtin_amdgcn_perm(a1[3], a1[2], psel);
            bfrag8 af = __builtin_bit_cast(bfrag8, fr);
            acc[t] = __builtin_amdgcn_mfma_f32_16x16x32_bf16(af, vh, acc[t], 0, 0, 0);
            acc[t] = __builtin_amdgcn_mfma_f32_16x16x32_bf16(af, vl, acc[t], 0, 0, 0);
        }
    }

    __syncthreads();   // all A-frag reads done before in-place f32 rewrite

    // rewrite attn rows rg*32..+31 as f32 = bf2f(hi)+bf2f(lo); 1KB coalesced per instr
    {
        int cb = (tid & 63) * 4;
        int rb = rg * 32 + (tid >> 6) * 8;
        #pragma unroll
        for (int jj = 0; jj < 8; ++jj) {
            size_t rowo = ((size_t)(bh * 1024 + rb + jj)) * 1024;
            #pragma unroll
            for (int c = 0; c < 4; ++c) {
                uint4v u = *(const uint4v*)(attnp + rowo + cb + c * 256);
                float4 f;
                f.x = __builtin_bit_cast(float, u[0] << 16) + __builtin_bit_cast(float, u[0] & 0xffff0000u);
                f.y = __builtin_bit_cast(float, u[1] << 16) + __builtin_bit_cast(float, u[1] & 0xffff0000u);
                f.z = __builtin_bit_cast(float, u[2] << 16) + __builtin_bit_cast(float, u[2] & 0xffff0000u);
                f.w = __builtin_bit_cast(float, u[3] << 16) + __builtin_bit_cast(float, u[3] & 0xffff0000u);
                *(float4*)(attnf + rowo + cb + c * 256) = f;
            }
        }
    }

    int b = bh >> 3, h = bh & 7;
    #pragma unroll
    for (int t = 0; t < 4; ++t) {
        #pragma unroll
        for (int q = 0; q < 4; ++q) {
            float v = acc[t][q] + __shfl_xor(acc[t][q], 32);   // hi rows + lo rows
            if (lane < 32) {
                int row = rg * 32 + t * 8 + (lane >> 4) * 4 + q;
                oh[(b * 1024 + row) * 512 + h * 64 + w * 16 + ar] = v;
            }
        }
    }
}

// ---------------- K_G: out = oh @ W_out + b_out; 512 thr, 1 col x 8 rows ----------------
__global__ __launch_bounds__(512) void k_out(const float* __restrict__ oh,
                                             const float* __restrict__ Wout,
                                             const float* __restrict__ bout,
                                             float* __restrict__ out) {
    __shared__ float xs[8 * 512];
    int tid = threadIdx.x;
    int i0 = blockIdx.x * 8;                 // 256 blocks
    const float4* xg = (const float4*)(oh + i0 * 512);
    float4* xs4 = (float4*)xs;
    #pragma unroll
    for (int j = 0; j < 2; ++j) xs4[j * 512 + tid] = xg[j * 512 + tid];
    __syncthreads();

    int col = tid;
    float a[8];
    #pragma unroll
    for (int r = 0; r < 8; ++r) a[r] = 0.f;
    const float* wp = Wout + col;
    for (int c4 = 0; c4 < 128; ++c4) {
        float w0 = wp[(c4 * 4 + 0) * 512];
        float w1 = wp[(c4 * 4 + 1) * 512];
        float w2 = wp[(c4 * 4 + 2) * 512];
        float w3 = wp[(c4 * 4 + 3) * 512];
        #pragma unroll
        for (int r = 0; r < 8; ++r) {
            float4 xv = *(const float4*)(xs + r * 512 + c4 * 4);
            a[r] = fmaf(xv.x, w0, fmaf(xv.y, w1, fmaf(xv.z, w2, fmaf(xv.w, w3, a[r]))));
        }
    }
    float bias = bout[col];
    #pragma unroll
    for (int r = 0; r < 8; ++r) out[(i0 + r) * 512 + col] = a[r] + bias;
}

extern "C" void kernel_launch(void* const* d_in, const int* in_sizes, int n_in,
                              void* d_out, int out_size, void* d_ws, size_t ws_size,
                              hipStream_t stream) {
    const float* x     = (const float*)d_in[0];
    const float* Wqkv  = (const float*)d_in[1];
    const float* theta = (const float*)d_in[2];
    const float* Wout  = (const float*)d_in[3];
    const float* bout  = (const float*)d_in[4];

    float* out  = (float*)d_out;                  // [2,1024,512]
    float* attn = out + 2 * 1024 * 512;           // [2,8,1024,1024]
    unsigned* attnp = (unsigned*)attn;            // packed (lo<<16|hi) staging, in place

    float* ws  = (float*)d_ws;
    float* Wqp = ws;                               // 32768
    float* Wkp = ws + 32768;                       // 32768
    float* qp  = ws + 65536;                       // 131072
    float* kp  = ws + 196608;                      // 131072
    unsigned short* vThi = (unsigned short*)(ws + 327680);   // 1,048,576 u16
    unsigned short* vTlo = (unsigned short*)(ws + 851968);   // 1,048,576 u16
    float* vnat = ws + 1376256;                    // 1048576 (aliases oh; vnat dead before k_pv writes oh)
    float* oh   = ws + 1376256;
    float* Wv   = ws + 2424832;                    // 262144

    k_wproj     <<<128,  256, 0, stream>>>(Wqkv, theta, Wqp, Wkp, Wv);
    k_qkp       <<<512,  256, 0, stream>>>(x, Wqp, Wkp, qp, kp);
    k_vproj_nat <<<256,  512, 0, stream>>>(x, Wv, vnat);
    k_vT        <<<256,  256, 0, stream>>>(vnat, vThi, vTlo);
    k_attn      <<<2048, 512, 0, stream>>>(qp, kp, attnp);
    k_pv        <<<512,  256, 0, stream>>>(attnp, vThi, vTlo, attn, oh);
    k_out       <<<256,  512, 0, stream>>>(oh, Wout, bout, out);
}

// Round 12
// 194.346 us; speedup vs baseline: 1.1392x; 1.1392x over previous
//
#include <hip/hip_runtime.h>
#include <hip/hip_bf16.h>

// Sizes (fixed): b=2, n=1024, dim=512, h=8, L=8, dh=64
// exp(-d2/T) with T=0.1 -> exp2(C*d2), C = -10*log2(e)
#define CEXP (-14.4269504088896340736f)

typedef __attribute__((ext_vector_type(8))) short bfrag8;   // 8 bf16 (4 VGPR) MFMA operand
typedef __attribute__((ext_vector_type(4))) float fvec4;    // MFMA accumulator / 16B vec
typedef __attribute__((ext_vector_type(8))) unsigned short ushort8;

__device__ inline unsigned short f2bf(float f) {            // RNE float->bf16
    unsigned u = __builtin_bit_cast(unsigned, f);
    u += 0x7fffu + ((u >> 16) & 1u);
    return (unsigned short)(u >> 16);
}
__device__ inline float bf2f(unsigned short h) {
    unsigned u = ((unsigned)h) << 16;
    return __builtin_bit_cast(float, u);
}

// Wave64 sum via DPP (rocPRIM pattern). ctrl/rmask immediates via template params.
template <int CTRL, int RMASK>
__device__ __forceinline__ float dpp_add(float v) {
    int m = __builtin_amdgcn_update_dpp(0, __builtin_bit_cast(int, v), CTRL, RMASK, 0xf, true);
    return v + __builtin_bit_cast(float, m);
}
__device__ __forceinline__ float wave_sum64(float v) {
    v = dpp_add<0xB1,  0xf>(v);   // quad_perm(1,0,3,2)
    v = dpp_add<0x4E,  0xf>(v);   // quad_perm(2,3,0,1)
    v = dpp_add<0x141, 0xf>(v);   // row_half_mirror
    v = dpp_add<0x140, 0xf>(v);   // row_mirror
    v = dpp_add<0x142, 0xa>(v);   // row_bcast15 into rows 1,3
    v = dpp_add<0x143, 0xc>(v);   // row_bcast31 into rows 2,3
    return __builtin_bit_cast(float, __builtin_amdgcn_readlane(__builtin_bit_cast(int, v), 63));
}

// ---------------- K_B: Wqp/Wkp = Wq/Wk projected on normalized theta; extract Wv ----
__global__ __launch_bounds__(256) void k_wproj(const float* __restrict__ Wqkv,
                                               const float* __restrict__ theta,
                                               float* __restrict__ Wqp,
                                               float* __restrict__ Wkp,
                                               float* __restrict__ Wv) {
    __shared__ float th_s[64 * 65];
    int tid = threadIdx.x;
    int hl = tid & 63, cl = tid >> 6;
    #pragma unroll
    for (int i = 0; i < 16; ++i) {
        int r = cl * 16 + i;
        th_s[r * 65 + hl] = theta[r * 64 + hl];
    }
    __syncthreads();
    const float* ts = th_s + hl * 65;
    float ss = 0.f;
    #pragma unroll 8
    for (int d = 0; d < 64; ++d) ss = fmaf(ts[d], ts[d], ss);
    float inv = rsqrtf(ss);
    int c = blockIdx.x * 4 + cl;
    int h = hl >> 3;
    const float* wq = Wqkv + c * 1536 + h * 64;
    const float* wk = wq + 512;
    float aq = 0.f, ak = 0.f;
    #pragma unroll 4
    for (int d = 0; d < 64; ++d) {
        float tv = ts[d];
        aq = fmaf(wq[d], tv, aq);
        ak = fmaf(wk[d], tv, ak);
    }
    Wqp[c * 64 + hl] = aq * inv;
    Wkp[c * 64 + hl] = ak * inv;

    int c0 = blockIdx.x * 4;
    const float4* src = (const float4*)(Wqkv + 1024);
    float4* dst = (float4*)Wv;
    #pragma unroll
    for (int j = 0; j < 2; ++j) {
        int idx = j * 256 + tid;
        int cr = c0 + (idx >> 7), o4 = idx & 127;
        dst[cr * 128 + o4] = src[cr * 384 + o4];
    }
}

// ---------------- K_C: qp/kp = scale * x @ W{q,k}p, layout [bh][l][n] ----------------
__global__ __launch_bounds__(256) void k_qkp(const float* __restrict__ x,
                                             const float* __restrict__ Wqp,
                                             const float* __restrict__ Wkp,
                                             float* __restrict__ qp,
                                             float* __restrict__ kp) {
    __shared__ float xs[4 * 512];
    int tid = threadIdx.x;
    int i0 = blockIdx.x * 4;                 // 512 blocks
    const float4* xg = (const float4*)(x + i0 * 512);
    float4* xs4 = (float4*)xs;
    #pragma unroll
    for (int j = 0; j < 2; ++j) xs4[j * 256 + tid] = xg[j * 256 + tid];
    __syncthreads();

    int t  = tid & 127;
    int rg = tid >> 7;
    int hl = t & 63;
    const float* Bm = (t & 64) ? Wkp : Wqp;
    const float* xr = xs + rg * 2 * 512;
    float a[2] = {0.f, 0.f};
    for (int c4 = 0; c4 < 128; ++c4) {
        float b0 = Bm[(c4 * 4 + 0) * 64 + hl];
        float b1 = Bm[(c4 * 4 + 1) * 64 + hl];
        float b2 = Bm[(c4 * 4 + 2) * 64 + hl];
        float b3 = Bm[(c4 * 4 + 3) * 64 + hl];
        #pragma unroll
        for (int r = 0; r < 2; ++r) {
            float4 xv = *(const float4*)(xr + r * 512 + c4 * 4);
            a[r] = fmaf(xv.x, b0, fmaf(xv.y, b1, fmaf(xv.z, b2, fmaf(xv.w, b3, a[r]))));
        }
    }
    int h = hl >> 3, l = hl & 7;
    float* dst = (t & 64) ? kp : qp;
    #pragma unroll
    for (int r = 0; r < 2; ++r) {
        int row = i0 + rg * 2 + r;
        int b = row >> 10, i = row & 1023;
        dst[((b * 8 + h) * 8 + l) * 1024 + i] = a[r] * 0.125f;
    }
}

// ---------------- K_D: vT = (x @ Wv)^T as bf16 hi/lo, [bh][d][n]; direct packed stores --
// 512 thr, 1 col x 8 consecutive rows -> two 16B ushort8 stores per thread in vT layout.
__global__ __launch_bounds__(512) void k_vproj(const float* __restrict__ x,
                                               const float* __restrict__ Wv,
                                               unsigned short* __restrict__ vThi,
                                               unsigned short* __restrict__ vTlo) {
    __shared__ float xs[8 * 512];
    int tid = threadIdx.x;
    int i0 = blockIdx.x * 8;                 // 256 blocks
    const float4* xg = (const float4*)(x + i0 * 512);
    float4* xs4 = (float4*)xs;
    #pragma unroll
    for (int j = 0; j < 2; ++j) xs4[j * 512 + tid] = xg[j * 512 + tid];
    __syncthreads();

    int col = tid;
    float a[8];
    #pragma unroll
    for (int r = 0; r < 8; ++r) a[r] = 0.f;
    const float* wp = Wv + col;
    for (int c4 = 0; c4 < 128; ++c4) {
        float w0 = wp[(c4 * 4 + 0) * 512];
        float w1 = wp[(c4 * 4 + 1) * 512];
        float w2 = wp[(c4 * 4 + 2) * 512];
        float w3 = wp[(c4 * 4 + 3) * 512];
        #pragma unroll
        for (int r = 0; r < 8; ++r) {
            float4 xv = *(const float4*)(xs + r * 512 + c4 * 4);
            a[r] = fmaf(xv.x, w0, fmaf(xv.y, w1, fmaf(xv.z, w2, fmaf(xv.w, w3, a[r]))));
        }
    }
    int h = col >> 6, d = col & 63;
    int b = i0 >> 10, ib = i0 & 1023;
    ushort8 vh, vl;
    #pragma unroll
    for (int r = 0; r < 8; ++r) {
        unsigned short hi = f2bf(a[r]);
        vh[r] = hi;
        vl[r] = f2bf(a[r] - bf2f(hi));
    }
    size_t off = (size_t)(b * 8 + h) * 65536 + (size_t)d * 1024 + ib;
    *(ushort8*)(vThi + off) = vh;
    *(ushort8*)(vTlo + off) = vl;
}

// ---------------- K_E: fused attention rows + MFMA PV; 512 thr / 8 waves ----------------
// Phase 1: wave w owns row rowbase+w; kv2 = CEXP*kv^2 precomputed in LDS (shared by all
// 8 row-waves). Phase 2: split-K across wave pairs (w, w+4), combine via LDS scratch.
__global__ __launch_bounds__(512) void k_attn_pv(const float* __restrict__ qp,
                                                 const float* __restrict__ kp,
                                                 const unsigned short* __restrict__ vThi,
                                                 const unsigned short* __restrict__ vTlo,
                                                 float* __restrict__ attn,
                                                 float* __restrict__ oh) {
    __shared__ float s_buf[8 * 1024];        // kp (f32) phase 1; P hi/lo bf16 [16][1024] phase 2
    __shared__ float kv2_s[8 * 1024];        // CEXP * kv^2, 32 KB
    __shared__ float sc[4 * 64 * 4];         // 4 KB split-K combine scratch
    int bx = blockIdx.x;                     // 2048
    int bh = bx >> 7;
    int rowbase = (bx & 127) * 8;
    int tid = threadIdx.x;
    int w = tid >> 6, lane = tid & 63;

    const float4* kp4 = (const float4*)(kp + bh * 8192);
    float4* kps4 = (float4*)s_buf;
    float4* kv2s4 = (float4*)kv2_s;
    #pragma unroll
    for (int k = 0; k < 4; ++k) {
        float4 v = kp4[k * 512 + tid];
        kps4[k * 512 + tid] = v;
        float4 v2;
        v2.x = CEXP * v.x * v.x; v2.y = CEXP * v.y * v.y;
        v2.z = CEXP * v.z * v.z; v2.w = CEXP * v.w * v.w;
        kv2s4[k * 512 + tid] = v2;
    }

    int r = rowbase + w;
    float qv[8];
    #pragma unroll
    for (int l = 0; l < 8; ++l) qv[l] = qp[bh * 8192 + l * 1024 + r];
    __syncthreads();

    float acc[16];                           // col = mm*256 + lane*4 + j
    #pragma unroll
    for (int m = 0; m < 16; ++m) acc[m] = 0.f;

    for (int l = 0; l < 8; ++l) {
        float4 kv4[4], k24[4];
        #pragma unroll
        for (int mm = 0; mm < 4; ++mm) {
            kv4[mm] = *(const float4*)(s_buf + l * 1024 + mm * 256 + lane * 4);
            k24[mm] = *(const float4*)(kv2_s + l * 1024 + mm * 256 + lane * 4);
        }
        float sq = -2.f * CEXP * qv[l];
        float e[16];
        #pragma unroll
        for (int mm = 0; mm < 4; ++mm) {
            e[mm * 4 + 0] = __builtin_amdgcn_exp2f(fmaf(sq, kv4[mm].x, k24[mm].x));
            e[mm * 4 + 1] = __builtin_amdgcn_exp2f(fmaf(sq, kv4[mm].y, k24[mm].y));
            e[mm * 4 + 2] = __builtin_amdgcn_exp2f(fmaf(sq, kv4[mm].z, k24[mm].z));
            e[mm * 4 + 3] = __builtin_amdgcn_exp2f(fmaf(sq, kv4[mm].w, k24[mm].w));
        }
        float s = (((e[0]+e[1])+(e[2]+e[3])) + ((e[4]+e[5])+(e[6]+e[7])))
                + (((e[8]+e[9])+(e[10]+e[11])) + ((e[12]+e[13])+(e[14]+e[15])));
        float inv = 0.125f * __builtin_amdgcn_rcpf(wave_sum64(s));
        #pragma unroll
        for (int m = 0; m < 16; ++m) acc[m] = fmaf(e[m], inv, acc[m]);
    }

    __syncthreads();   // all waves done reading kp from s_buf

    // stash P row w as bf16: hi -> row w, lo -> row w+8; XOR-swizzle j ^ (w<<3)
    // NOTE phase-1 acc layout: col = mm*256 + lane*4 + j  (m = mm*4+j)
    unsigned short* ps = (unsigned short*)s_buf;
    int swz = w << 3;
    #pragma unroll
    for (int m = 0; m < 16; ++m) {
        int j = (m >> 2) * 256 + lane * 4 + (m & 3);
        unsigned short hi = f2bf(acc[m]);
        ps[w * 1024 + (j ^ swz)]       = hi;
        ps[(w + 8) * 1024 + (j ^ swz)] = f2bf(acc[m] - bf2f(hi));
    }
    __syncthreads();

    // attn stores: fire-and-forget, drain under phase-2 compute. 16B coalesced.
    float* aR = attn + ((size_t)(bh * 1024 + r)) * 1024;
    #pragma unroll
    for (int mm = 0; mm < 4; ++mm) {
        fvec4 st;
        st[0] = acc[mm * 4 + 0]; st[1] = acc[mm * 4 + 1];
        st[2] = acc[mm * 4 + 2]; st[3] = acc[mm * 4 + 3];
        __builtin_nontemporal_store(st, (fvec4*)(aR + mm * 256 + lane * 4));
    }

    // Phase 2: wave w -> cols n0..n0+15, K-half kh; pairs (w, w+4) combine via LDS.
    int n0 = (w & 3) * 16;
    int kh = w >> 2;
    int ar  = lane & 15;
    int asw = (ar & 7) << 3;
    int ak  = (lane >> 4) * 8;
    const unsigned short* ap = ps + ar * 1024;
    size_t boff = (size_t)bh * 65536 + (size_t)(n0 + (lane & 15)) * 1024 + ak;
    const unsigned short* bh_p = vThi + boff;
    const unsigned short* bl_p = vTlo + boff;
    fvec4 c2 = {0.f, 0.f, 0.f, 0.f};
    #pragma unroll 4
    for (int s = kh * 16; s < kh * 16 + 16; ++s) {
        bfrag8 a  = *(const bfrag8*)(ap + ((s * 32 + ak) ^ asw));
        bfrag8 vh = *(const bfrag8*)(bh_p + s * 32);
        bfrag8 vl = *(const bfrag8*)(bl_p + s * 32);
        c2 = __builtin_amdgcn_mfma_f32_16x16x32_bf16(a, vh, c2, 0, 0, 0);
        c2 = __builtin_amdgcn_mfma_f32_16x16x32_bf16(a, vl, c2, 0, 0, 0);
    }
    if (w >= 4) {
        #pragma unroll
        for (int q = 0; q < 4; ++q) sc[(w - 4) * 256 + lane * 4 + q] = c2[q];
    }
    __syncthreads();
    if (w < 4) {
        int b = bh >> 3, h = bh & 7;
        #pragma unroll
        for (int q = 0; q < 4; ++q) {
            float t = c2[q] + sc[w * 256 + lane * 4 + q];
            t += __shfl_xor(t, 32);               // hi row + lo row
            if (lane < 32) {
                int row = rowbase + (lane >> 4) * 4 + q;
                oh[(b * 1024 + row) * 512 + h * 64 + n0 + (lane & 15)] = t;
            }
        }
    }
}

// ---------------- K_G: out = oh @ W_out + b_out; 512 thr, 1 col x 8 rows ----------------
__global__ __launch_bounds__(512) void k_out(const float* __restrict__ oh,
                                             const float* __restrict__ Wout,
                                             const float* __restrict__ bout,
                                             float* __restrict__ out) {
    __shared__ float xs[8 * 512];
    int tid = threadIdx.x;
    int i0 = blockIdx.x * 8;                 // 256 blocks
    const float4* xg = (const float4*)(oh + i0 * 512);
    float4* xs4 = (float4*)xs;
    #pragma unroll
    for (int j = 0; j < 2; ++j) xs4[j * 512 + tid] = xg[j * 512 + tid];
    __syncthreads();

    int col = tid;
    float a[8];
    #pragma unroll
    for (int r = 0; r < 8; ++r) a[r] = 0.f;
    const float* wp = Wout + col;
    for (int c4 = 0; c4 < 128; ++c4) {
        float w0 = wp[(c4 * 4 + 0) * 512];
        float w1 = wp[(c4 * 4 + 1) * 512];
        float w2 = wp[(c4 * 4 + 2) * 512];
        float w3 = wp[(c4 * 4 + 3) * 512];
        #pragma unroll
        for (int r = 0; r < 8; ++r) {
            float4 xv = *(const float4*)(xs + r * 512 + c4 * 4);
            a[r] = fmaf(xv.x, w0, fmaf(xv.y, w1, fmaf(xv.z, w2, fmaf(xv.w, w3, a[r]))));
        }
    }
    float bias = bout[col];
    #pragma unroll
    for (int r = 0; r < 8; ++r) out[(i0 + r) * 512 + col] = a[r] + bias;
}

extern "C" void kernel_launch(void* const* d_in, const int* in_sizes, int n_in,
                              void* d_out, int out_size, void* d_ws, size_t ws_size,
                              hipStream_t stream) {
    const float* x     = (const float*)d_in[0];
    const float* Wqkv  = (const float*)d_in[1];
    const float* theta = (const float*)d_in[2];
    const float* Wout  = (const float*)d_in[3];
    const float* bout  = (const float*)d_in[4];

    float* out  = (float*)d_out;                  // [2,1024,512]
    float* attn = out + 2 * 1024 * 512;           // [2,8,1024,1024]

    float* ws  = (float*)d_ws;
    float* Wqp = ws;                               // 32768
    float* Wkp = ws + 32768;                       // 32768
    float* qp  = ws + 65536;                       // 131072
    float* kp  = ws + 196608;                      // 131072
    unsigned short* vThi = (unsigned short*)(ws + 327680);   // 1,048,576 u16
    unsigned short* vTlo = (unsigned short*)(ws + 851968);   // 1,048,576 u16
    float* oh   = ws + 1376256;                    // 1048576
    float* Wv   = ws + 2424832;                    // 262144

    k_wproj   <<<128,  256, 0, stream>>>(Wqkv, theta, Wqp, Wkp, Wv);
    k_qkp     <<<512,  256, 0, stream>>>(x, Wqp, Wkp, qp, kp);
    k_vproj   <<<256,  512, 0, stream>>>(x, Wv, vThi, vTlo);
    k_attn_pv <<<2048, 512, 0, stream>>>(qp, kp, vThi, vTlo, attn, oh);
    k_out     <<<256,  512, 0, stream>>>(oh, Wout, bout, out);
}

// Round 13
// 154.445 us; speedup vs baseline: 1.4335x; 1.2583x over previous
//
#include <hip/hip_runtime.h>
#include <hip/hip_bf16.h>

// Sizes (fixed): b=2, n=1024, dim=512, h=8, L=8, dh=64
// exp(-d2/T) with T=0.1 -> exp2(C*d2), C = -10*log2(e)
#define CEXP (-14.4269504088896340736f)

typedef __attribute__((ext_vector_type(8))) short bfrag8;   // 8 bf16 (4 VGPR) MFMA operand
typedef __attribute__((ext_vector_type(4))) float fvec4;    // MFMA accumulator / 16B vec
typedef __attribute__((ext_vector_type(8))) unsigned short ushort8;

__device__ inline unsigned short f2bf(float f) {            // RNE float->bf16
    unsigned u = __builtin_bit_cast(unsigned, f);
    u += 0x7fffu + ((u >> 16) & 1u);
    return (unsigned short)(u >> 16);
}
__device__ inline float bf2f(unsigned short h) {
    unsigned u = ((unsigned)h) << 16;
    return __builtin_bit_cast(float, u);
}

// Wave64 sum via DPP (rocPRIM pattern). ctrl/rmask immediates via template params.
template <int CTRL, int RMASK>
__device__ __forceinline__ float dpp_add(float v) {
    int m = __builtin_amdgcn_update_dpp(0, __builtin_bit_cast(int, v), CTRL, RMASK, 0xf, true);
    return v + __builtin_bit_cast(float, m);
}
__device__ __forceinline__ float wave_sum64(float v) {
    v = dpp_add<0xB1,  0xf>(v);   // quad_perm(1,0,3,2)
    v = dpp_add<0x4E,  0xf>(v);   // quad_perm(2,3,0,1)
    v = dpp_add<0x141, 0xf>(v);   // row_half_mirror
    v = dpp_add<0x140, 0xf>(v);   // row_mirror
    v = dpp_add<0x142, 0xa>(v);   // row_bcast15 into rows 1,3
    v = dpp_add<0x143, 0xc>(v);   // row_bcast31 into rows 2,3
    return __builtin_bit_cast(float, __builtin_amdgcn_readlane(__builtin_bit_cast(int, v), 63));
}

// ---------------- K_B: Wqp/Wkp = Wq/Wk projected on normalized theta; extract Wv ----
__global__ __launch_bounds__(256) void k_wproj(const float* __restrict__ Wqkv,
                                               const float* __restrict__ theta,
                                               float* __restrict__ Wqp,
                                               float* __restrict__ Wkp,
                                               float* __restrict__ Wv) {
    __shared__ float th_s[64 * 65];
    int tid = threadIdx.x;
    int hl = tid & 63, cl = tid >> 6;
    #pragma unroll
    for (int i = 0; i < 16; ++i) {
        int r = cl * 16 + i;
        th_s[r * 65 + hl] = theta[r * 64 + hl];
    }
    __syncthreads();
    const float* ts = th_s + hl * 65;
    float ss = 0.f;
    #pragma unroll 8
    for (int d = 0; d < 64; ++d) ss = fmaf(ts[d], ts[d], ss);
    float inv = rsqrtf(ss);
    int c = blockIdx.x * 4 + cl;
    int h = hl >> 3;
    const float* wq = Wqkv + c * 1536 + h * 64;
    const float* wk = wq + 512;
    float aq = 0.f, ak = 0.f;
    #pragma unroll 4
    for (int d = 0; d < 64; ++d) {
        float tv = ts[d];
        aq = fmaf(wq[d], tv, aq);
        ak = fmaf(wk[d], tv, ak);
    }
    Wqp[c * 64 + hl] = aq * inv;
    Wkp[c * 64 + hl] = ak * inv;

    int c0 = blockIdx.x * 4;
    const float4* src = (const float4*)(Wqkv + 1024);
    float4* dst = (float4*)Wv;
    #pragma unroll
    for (int j = 0; j < 2; ++j) {
        int idx = j * 256 + tid;
        int cr = c0 + (idx >> 7), o4 = idx & 127;
        dst[cr * 128 + o4] = src[cr * 384 + o4];
    }
}

// ---------------- K_C: qp/kp = scale * x @ W{q,k}p, layout [bh][l][n] ----------------
__global__ __launch_bounds__(256) void k_qkp(const float* __restrict__ x,
                                             const float* __restrict__ Wqp,
                                             const float* __restrict__ Wkp,
                                             float* __restrict__ qp,
                                             float* __restrict__ kp) {
    __shared__ float xs[4 * 512];
    int tid = threadIdx.x;
    int i0 = blockIdx.x * 4;                 // 512 blocks
    const float4* xg = (const float4*)(x + i0 * 512);
    float4* xs4 = (float4*)xs;
    #pragma unroll
    for (int j = 0; j < 2; ++j) xs4[j * 256 + tid] = xg[j * 256 + tid];
    __syncthreads();

    int t  = tid & 127;
    int rg = tid >> 7;
    int hl = t & 63;
    const float* Bm = (t & 64) ? Wkp : Wqp;
    const float* xr = xs + rg * 2 * 512;
    float a[2] = {0.f, 0.f};
    for (int c4 = 0; c4 < 128; ++c4) {
        float b0 = Bm[(c4 * 4 + 0) * 64 + hl];
        float b1 = Bm[(c4 * 4 + 1) * 64 + hl];
        float b2 = Bm[(c4 * 4 + 2) * 64 + hl];
        float b3 = Bm[(c4 * 4 + 3) * 64 + hl];
        #pragma unroll
        for (int r = 0; r < 2; ++r) {
            float4 xv = *(const float4*)(xr + r * 512 + c4 * 4);
            a[r] = fmaf(xv.x, b0, fmaf(xv.y, b1, fmaf(xv.z, b2, fmaf(xv.w, b3, a[r]))));
        }
    }
    int h = hl >> 3, l = hl & 7;
    float* dst = (t & 64) ? kp : qp;
    #pragma unroll
    for (int r = 0; r < 2; ++r) {
        int row = i0 + rg * 2 + r;
        int b = row >> 10, i = row & 1023;
        dst[((b * 8 + h) * 8 + l) * 1024 + i] = a[r] * 0.125f;
    }
}

// ---------------- K_D: vT = (x @ Wv)^T as bf16 hi/lo, [bh][d][n] --------------------
// 512 blocks = 256 row-tiles x 2 col-halves; 256 thr; thread = 1 col x 8 rows;
// two packed 16B ushort8 stores per thread directly in vT layout.
__global__ __launch_bounds__(256) void k_vproj(const float* __restrict__ x,
                                               const float* __restrict__ Wv,
                                               unsigned short* __restrict__ vThi,
                                               unsigned short* __restrict__ vTlo) {
    __shared__ float xs[8 * 512];
    int tid = threadIdx.x;
    int blk = blockIdx.x;                    // 512
    int ch = blk & 1;
    int i0 = (blk >> 1) * 8;
    const float4* xg = (const float4*)(x + i0 * 512);
    float4* xs4 = (float4*)xs;
    #pragma unroll
    for (int j = 0; j < 4; ++j) xs4[j * 256 + tid] = xg[j * 256 + tid];
    __syncthreads();

    int col = ch * 256 + tid;
    float a[8];
    #pragma unroll
    for (int r = 0; r < 8; ++r) a[r] = 0.f;
    const float* wp = Wv + col;
    for (int c4 = 0; c4 < 128; ++c4) {
        float w0 = wp[(c4 * 4 + 0) * 512];
        float w1 = wp[(c4 * 4 + 1) * 512];
        float w2 = wp[(c4 * 4 + 2) * 512];
        float w3 = wp[(c4 * 4 + 3) * 512];
        #pragma unroll
        for (int r = 0; r < 8; ++r) {
            float4 xv = *(const float4*)(xs + r * 512 + c4 * 4);
            a[r] = fmaf(xv.x, w0, fmaf(xv.y, w1, fmaf(xv.z, w2, fmaf(xv.w, w3, a[r]))));
        }
    }
    int h = col >> 6, d = col & 63;
    int b = i0 >> 10, ib = i0 & 1023;
    ushort8 vh, vl;
    #pragma unroll
    for (int r = 0; r < 8; ++r) {
        unsigned short hi = f2bf(a[r]);
        vh[r] = hi;
        vl[r] = f2bf(a[r] - bf2f(hi));
    }
    size_t off = (size_t)(b * 8 + h) * 65536 + (size_t)d * 1024 + ib;
    *(ushort8*)(vThi + off) = vh;
    *(ushort8*)(vTlo + off) = vl;
}

// ---------------- K_E: fused attention rows + MFMA PV; 512 thr / 8 waves (r9 exact) ----
// Wave w owns row rowbase+w in phase 1. Phase 2: split-K across wave pairs (w, w+4).
__global__ __launch_bounds__(512) void k_attn_pv(const float* __restrict__ qp,
                                                 const float* __restrict__ kp,
                                                 const unsigned short* __restrict__ vThi,
                                                 const unsigned short* __restrict__ vTlo,
                                                 float* __restrict__ attn,
                                                 float* __restrict__ oh) {
    __shared__ float s_buf[8 * 1024];        // kp (f32) phase 1; P hi/lo bf16 [16][1024] phase 2
    __shared__ float sc[4 * 64 * 4];         // 4 KB split-K combine scratch
    int bx = blockIdx.x;                     // 2048
    int bh = bx >> 7;
    int rowbase = (bx & 127) * 8;
    int tid = threadIdx.x;
    int w = tid >> 6, lane = tid & 63;

    const float4* kp4 = (const float4*)(kp + bh * 8192);
    float4* kps4 = (float4*)s_buf;
    #pragma unroll
    for (int k = 0; k < 4; ++k) kps4[k * 512 + tid] = kp4[k * 512 + tid];

    int r = rowbase + w;
    float qv[8];
    #pragma unroll
    for (int l = 0; l < 8; ++l) qv[l] = qp[bh * 8192 + l * 1024 + r];
    __syncthreads();

    float acc[16];
    #pragma unroll
    for (int m = 0; m < 16; ++m) acc[m] = 0.f;

    for (int l = 0; l < 8; ++l) {
        float kv[16], kv2[16], e[16];
        #pragma unroll
        for (int m = 0; m < 16; ++m) {
            kv[m] = s_buf[l * 1024 + m * 64 + lane];
            kv2[m] = CEXP * kv[m] * kv[m];       // C*k^2
        }
        float sq = -2.f * CEXP * qv[l];
        #pragma unroll
        for (int m = 0; m < 16; ++m) e[m] = __builtin_amdgcn_exp2f(fmaf(sq, kv[m], kv2[m]));
        float s = (((e[0]+e[1])+(e[2]+e[3])) + ((e[4]+e[5])+(e[6]+e[7])))
                + (((e[8]+e[9])+(e[10]+e[11])) + ((e[12]+e[13])+(e[14]+e[15])));
        float inv = 0.125f * __builtin_amdgcn_rcpf(wave_sum64(s));
        #pragma unroll
        for (int m = 0; m < 16; ++m) acc[m] = fmaf(e[m], inv, acc[m]);
    }

    __syncthreads();   // all waves done reading kp from s_buf

    // stash P row w as bf16: hi -> row w, lo -> row w+8; XOR-swizzle j ^ (w<<3)
    unsigned short* ps = (unsigned short*)s_buf;
    int swz = w << 3;
    #pragma unroll
    for (int m = 0; m < 16; ++m) {
        int j = m * 64 + lane;
        unsigned short hi = f2bf(acc[m]);
        ps[w * 1024 + (j ^ swz)]       = hi;
        ps[(w + 8) * 1024 + (j ^ swz)] = f2bf(acc[m] - bf2f(hi));
    }
    __syncthreads();

    // attn stores: fire-and-forget, drain under phase-2 compute.
    float* aR = attn + ((size_t)(bh * 1024 + r)) * 1024 + lane;
    #pragma unroll
    for (int m = 0; m < 16; ++m) __builtin_nontemporal_store(acc[m], aR + m * 64);

    // Phase 2: wave w -> cols n0..n0+15, K-half kh; pairs (w, w+4) combine via LDS.
    int n0 = (w & 3) * 16;
    int kh = w >> 2;
    int ar  = lane & 15;
    int asw = (ar & 7) << 3;
    int ak  = (lane >> 4) * 8;
    const unsigned short* ap = ps + ar * 1024;
    size_t boff = (size_t)bh * 65536 + (size_t)(n0 + (lane & 15)) * 1024 + ak;
    const unsigned short* bh_p = vThi + boff;
    const unsigned short* bl_p = vTlo + boff;
    fvec4 c2 = {0.f, 0.f, 0.f, 0.f};
    #pragma unroll 4
    for (int s = kh * 16; s < kh * 16 + 16; ++s) {
        bfrag8 a  = *(const bfrag8*)(ap + ((s * 32 + ak) ^ asw));
        bfrag8 vh = *(const bfrag8*)(bh_p + s * 32);
        bfrag8 vl = *(const bfrag8*)(bl_p + s * 32);
        c2 = __builtin_amdgcn_mfma_f32_16x16x32_bf16(a, vh, c2, 0, 0, 0);
        c2 = __builtin_amdgcn_mfma_f32_16x16x32_bf16(a, vl, c2, 0, 0, 0);
    }
    if (w >= 4) {
        #pragma unroll
        for (int q = 0; q < 4; ++q) sc[(w - 4) * 256 + lane * 4 + q] = c2[q];
    }
    __syncthreads();
    if (w < 4) {
        int b = bh >> 3, h = bh & 7;
        #pragma unroll
        for (int q = 0; q < 4; ++q) {
            float t = c2[q] + sc[w * 256 + lane * 4 + q];
            t += __shfl_xor(t, 32);               // hi row + lo row
            if (lane < 32) {
                int row = rowbase + (lane >> 4) * 4 + q;
                oh[(b * 1024 + row) * 512 + h * 64 + n0 + (lane & 15)] = t;
            }
        }
    }
}

// ---------------- K_G: out = oh @ W_out + b_out ----------------------------------------
// 512 blocks = 256 row-tiles x 2 col-halves; 256 thr; thread = 1 col x 8 rows.
__global__ __launch_bounds__(256) void k_out(const float* __restrict__ oh,
                                             const float* __restrict__ Wout,
                                             const float* __restrict__ bout,
                                             float* __restrict__ out) {
    __shared__ float xs[8 * 512];
    int tid = threadIdx.x;
    int blk = blockIdx.x;                    // 512
    int ch = blk & 1;
    int i0 = (blk >> 1) * 8;
    const float4* xg = (const float4*)(oh + i0 * 512);
    float4* xs4 = (float4*)xs;
    #pragma unroll
    for (int j = 0; j < 4; ++j) xs4[j * 256 + tid] = xg[j * 256 + tid];
    __syncthreads();

    int col = ch * 256 + tid;
    float a[8];
    #pragma unroll
    for (int r = 0; r < 8; ++r) a[r] = 0.f;
    const float* wp = Wout + col;
    for (int c4 = 0; c4 < 128; ++c4) {
        float w0 = wp[(c4 * 4 + 0) * 512];
        float w1 = wp[(c4 * 4 + 1) * 512];
        float w2 = wp[(c4 * 4 + 2) * 512];
        float w3 = wp[(c4 * 4 + 3) * 512];
        #pragma unroll
        for (int r = 0; r < 8; ++r) {
            float4 xv = *(const float4*)(xs + r * 512 + c4 * 4);
            a[r] = fmaf(xv.x, w0, fmaf(xv.y, w1, fmaf(xv.z, w2, fmaf(xv.w, w3, a[r]))));
        }
    }
    float bias = bout[col];
    #pragma unroll
    for (int r = 0; r < 8; ++r) out[(i0 + r) * 512 + col] = a[r] + bias;
}

extern "C" void kernel_launch(void* const* d_in, const int* in_sizes, int n_in,
                              void* d_out, int out_size, void* d_ws, size_t ws_size,
                              hipStream_t stream) {
    const float* x     = (const float*)d_in[0];
    const float* Wqkv  = (const float*)d_in[1];
    const float* theta = (const float*)d_in[2];
    const float* Wout  = (const float*)d_in[3];
    const float* bout  = (const float*)d_in[4];

    float* out  = (float*)d_out;                  // [2,1024,512]
    float* attn = out + 2 * 1024 * 512;           // [2,8,1024,1024]

    float* ws  = (float*)d_ws;
    float* Wqp = ws;                               // 32768
    float* Wkp = ws + 32768;                       // 32768
    float* qp  = ws + 65536;                       // 131072
    float* kp  = ws + 196608;                      // 131072
    unsigned short* vThi = (unsigned short*)(ws + 327680);   // 1,048,576 u16
    unsigned short* vTlo = (unsigned short*)(ws + 851968);   // 1,048,576 u16
    float* oh   = ws + 1376256;                    // 1048576
    float* Wv   = ws + 2424832;                    // 262144

    k_wproj   <<<128,  256, 0, stream>>>(Wqkv, theta, Wqp, Wkp, Wv);
    k_qkp     <<<512,  256, 0, stream>>>(x, Wqp, Wkp, qp, kp);
    k_vproj   <<<512,  256, 0, stream>>>(x, Wv, vThi, vTlo);
    k_attn_pv <<<2048, 512, 0, stream>>>(qp, kp, vThi, vTlo, attn, oh);
    k_out     <<<512,  256, 0, stream>>>(oh, Wout, bout, out);
}

// Round 14
// 137.827 us; speedup vs baseline: 1.6064x; 1.1206x over previous
//
#include <hip/hip_runtime.h>
#include <hip/hip_bf16.h>

// Sizes (fixed): b=2, n=1024, dim=512, h=8, L=8, dh=64
// exp(-d2/T) with T=0.1 -> exp2(C*d2), C = -10*log2(e)
#define CEXP (-14.4269504088896340736f)

typedef __attribute__((ext_vector_type(8))) short bfrag8;   // 8 bf16 (4 VGPR) MFMA operand
typedef __attribute__((ext_vector_type(4))) float fvec4;    // MFMA accumulator / 16B vec
typedef __attribute__((ext_vector_type(8))) unsigned short ushort8;

__device__ inline unsigned short f2bf(float f) {            // RNE float->bf16
    unsigned u = __builtin_bit_cast(unsigned, f);
    u += 0x7fffu + ((u >> 16) & 1u);
    return (unsigned short)(u >> 16);
}
__device__ inline float bf2f(unsigned short h) {
    unsigned u = ((unsigned)h) << 16;
    return __builtin_bit_cast(float, u);
}

// Wave64 sum via DPP (rocPRIM pattern). ctrl/rmask immediates via template params.
template <int CTRL, int RMASK>
__device__ __forceinline__ float dpp_add(float v) {
    int m = __builtin_amdgcn_update_dpp(0, __builtin_bit_cast(int, v), CTRL, RMASK, 0xf, true);
    return v + __builtin_bit_cast(float, m);
}
__device__ __forceinline__ float wave_sum64(float v) {
    v = dpp_add<0xB1,  0xf>(v);   // quad_perm(1,0,3,2)
    v = dpp_add<0x4E,  0xf>(v);   // quad_perm(2,3,0,1)
    v = dpp_add<0x141, 0xf>(v);   // row_half_mirror
    v = dpp_add<0x140, 0xf>(v);   // row_mirror
    v = dpp_add<0x142, 0xa>(v);   // row_bcast15 into rows 1,3
    v = dpp_add<0x143, 0xc>(v);   // row_bcast31 into rows 2,3
    return __builtin_bit_cast(float, __builtin_amdgcn_readlane(__builtin_bit_cast(int, v), 63));
}

// ---------------- K_B: Wqp/Wkp = Wq/Wk projected on normalized theta; extract Wv ----
__global__ __launch_bounds__(256) void k_wproj(const float* __restrict__ Wqkv,
                                               const float* __restrict__ theta,
                                               float* __restrict__ Wqp,
                                               float* __restrict__ Wkp,
                                               float* __restrict__ Wv) {
    __shared__ float th_s[64 * 65];
    int tid = threadIdx.x;
    int hl = tid & 63, cl = tid >> 6;
    #pragma unroll
    for (int i = 0; i < 16; ++i) {
        int r = cl * 16 + i;
        th_s[r * 65 + hl] = theta[r * 64 + hl];
    }
    __syncthreads();
    const float* ts = th_s + hl * 65;
    float ss = 0.f;
    #pragma unroll 8
    for (int d = 0; d < 64; ++d) ss = fmaf(ts[d], ts[d], ss);
    float inv = rsqrtf(ss);
    int c = blockIdx.x * 4 + cl;
    int h = hl >> 3;
    const float* wq = Wqkv + c * 1536 + h * 64;
    const float* wk = wq + 512;
    float aq = 0.f, ak = 0.f;
    #pragma unroll 4
    for (int d = 0; d < 64; ++d) {
        float tv = ts[d];
        aq = fmaf(wq[d], tv, aq);
        ak = fmaf(wk[d], tv, ak);
    }
    Wqp[c * 64 + hl] = aq * inv;
    Wkp[c * 64 + hl] = ak * inv;

    int c0 = blockIdx.x * 4;
    const float4* src = (const float4*)(Wqkv + 1024);
    float4* dst = (float4*)Wv;
    #pragma unroll
    for (int j = 0; j < 2; ++j) {
        int idx = j * 256 + tid;
        int cr = c0 + (idx >> 7), o4 = idx & 127;
        dst[cr * 128 + o4] = src[cr * 384 + o4];
    }
}

// ---------------- K_C: qp/kp = scale * x @ W{q,k}p, layout [bh][l][n] ----------------
// 512 blocks x 4 rows; 512 thr = 128 cols (64 q + 64 k) x 4 K-quarters; LDS combine;
// final float4 stores (4 consecutive rows per plane).
__global__ __launch_bounds__(512) void k_qkp(const float* __restrict__ x,
                                             const float* __restrict__ Wqp,
                                             const float* __restrict__ Wkp,
                                             float* __restrict__ qp,
                                             float* __restrict__ kp) {
    __shared__ float xs[4 * 512];            // 8 KB
    __shared__ float comb[4][128][4];        // 8 KB
    int tid = threadIdx.x;
    int i0 = blockIdx.x * 4;                 // 512 blocks
    const float4* xg = (const float4*)(x + i0 * 512);
    ((float4*)xs)[tid] = xg[tid];            // 512 float4 = 4 rows
    __syncthreads();

    int t  = tid & 127;
    int kh = tid >> 7;                       // 0..3
    int hl = t & 63;
    const float* Bm = (t & 64) ? Wkp : Wqp;
    float a[4] = {0.f, 0.f, 0.f, 0.f};
    int c4b = kh * 32;
    for (int c4 = c4b; c4 < c4b + 32; ++c4) {
        float b0 = Bm[(c4 * 4 + 0) * 64 + hl];
        float b1 = Bm[(c4 * 4 + 1) * 64 + hl];
        float b2 = Bm[(c4 * 4 + 2) * 64 + hl];
        float b3 = Bm[(c4 * 4 + 3) * 64 + hl];
        #pragma unroll
        for (int r = 0; r < 4; ++r) {
            float4 xv = *(const float4*)(xs + r * 512 + c4 * 4);
            a[r] = fmaf(xv.x, b0, fmaf(xv.y, b1, fmaf(xv.z, b2, fmaf(xv.w, b3, a[r]))));
        }
    }
    #pragma unroll
    for (int r = 0; r < 4; ++r) comb[kh][t][r] = a[r];
    __syncthreads();

    if (tid < 128) {
        int hl2 = tid & 63;
        int h = hl2 >> 3, l = hl2 & 7;
        float* dst = (tid & 64) ? kp : qp;
        int b = i0 >> 10, i = i0 & 1023;
        fvec4 st;
        #pragma unroll
        for (int r = 0; r < 4; ++r)
            st[r] = (comb[0][tid][r] + comb[1][tid][r] + comb[2][tid][r] + comb[3][tid][r]) * 0.125f;
        *(fvec4*)(dst + ((b * 8 + h) * 8 + l) * 1024 + i) = st;
    }
}

// ---------------- K_D: vT = (x @ Wv)^T as bf16 hi/lo, [bh][d][n] --------------------
// 1024 blocks = 256 row-tiles x 4 col-slices (128 cols); 256 thr = 128 cols x 2 K-halves;
// LDS combine; packed 16B ushort8 stores in vT layout.
__global__ __launch_bounds__(256) void k_vproj(const float* __restrict__ x,
                                               const float* __restrict__ Wv,
                                               unsigned short* __restrict__ vThi,
                                               unsigned short* __restrict__ vTlo) {
    __shared__ float xs[8 * 512];            // 16 KB
    __shared__ float comb[2][128][8];        // 8 KB
    int tid = threadIdx.x;
    int blk = blockIdx.x;                    // 1024
    int cs = blk & 3;
    int i0 = (blk >> 2) * 8;
    const float4* xg = (const float4*)(x + i0 * 512);
    float4* xs4 = (float4*)xs;
    #pragma unroll
    for (int j = 0; j < 4; ++j) xs4[j * 256 + tid] = xg[j * 256 + tid];
    __syncthreads();

    int t  = tid & 127;
    int kh = tid >> 7;                       // 0..1
    int col = cs * 128 + t;
    const float* wp = Wv + col;
    float a[8];
    #pragma unroll
    for (int r = 0; r < 8; ++r) a[r] = 0.f;
    int c4b = kh * 64;
    for (int c4 = c4b; c4 < c4b + 64; ++c4) {
        float w0 = wp[(c4 * 4 + 0) * 512];
        float w1 = wp[(c4 * 4 + 1) * 512];
        float w2 = wp[(c4 * 4 + 2) * 512];
        float w3 = wp[(c4 * 4 + 3) * 512];
        #pragma unroll
        for (int r = 0; r < 8; ++r) {
            float4 xv = *(const float4*)(xs + r * 512 + c4 * 4);
            a[r] = fmaf(xv.x, w0, fmaf(xv.y, w1, fmaf(xv.z, w2, fmaf(xv.w, w3, a[r]))));
        }
    }
    #pragma unroll
    for (int r = 0; r < 8; ++r) comb[kh][t][r] = a[r];
    __syncthreads();

    if (tid < 128) {
        int col2 = cs * 128 + tid;
        int h = col2 >> 6, d = col2 & 63;
        int b = i0 >> 10, ib = i0 & 1023;
        ushort8 vh, vl;
        #pragma unroll
        for (int r = 0; r < 8; ++r) {
            float v = comb[0][tid][r] + comb[1][tid][r];
            unsigned short hi = f2bf(v);
            vh[r] = hi;
            vl[r] = f2bf(v - bf2f(hi));
        }
        size_t off = (size_t)(b * 8 + h) * 65536 + (size_t)d * 1024 + ib;
        *(ushort8*)(vThi + off) = vh;
        *(ushort8*)(vTlo + off) = vl;
    }
}

// ---------------- K_E: fused attention rows + MFMA PV; 512 thr / 8 waves (r9 exact) ----
// Wave w owns row rowbase+w in phase 1. Phase 2: split-K across wave pairs (w, w+4).
__global__ __launch_bounds__(512) void k_attn_pv(const float* __restrict__ qp,
                                                 const float* __restrict__ kp,
                                                 const unsigned short* __restrict__ vThi,
                                                 const unsigned short* __restrict__ vTlo,
                                                 float* __restrict__ attn,
                                                 float* __restrict__ oh) {
    __shared__ float s_buf[8 * 1024];        // kp (f32) phase 1; P hi/lo bf16 [16][1024] phase 2
    __shared__ float sc[4 * 64 * 4];         // 4 KB split-K combine scratch
    int bx = blockIdx.x;                     // 2048
    int bh = bx >> 7;
    int rowbase = (bx & 127) * 8;
    int tid = threadIdx.x;
    int w = tid >> 6, lane = tid & 63;

    const float4* kp4 = (const float4*)(kp + bh * 8192);
    float4* kps4 = (float4*)s_buf;
    #pragma unroll
    for (int k = 0; k < 4; ++k) kps4[k * 512 + tid] = kp4[k * 512 + tid];

    int r = rowbase + w;
    float qv[8];
    #pragma unroll
    for (int l = 0; l < 8; ++l) qv[l] = qp[bh * 8192 + l * 1024 + r];
    __syncthreads();

    float acc[16];
    #pragma unroll
    for (int m = 0; m < 16; ++m) acc[m] = 0.f;

    for (int l = 0; l < 8; ++l) {
        float kv[16], kv2[16], e[16];
        #pragma unroll
        for (int m = 0; m < 16; ++m) {
            kv[m] = s_buf[l * 1024 + m * 64 + lane];
            kv2[m] = CEXP * kv[m] * kv[m];       // C*k^2
        }
        float sq = -2.f * CEXP * qv[l];
        #pragma unroll
        for (int m = 0; m < 16; ++m) e[m] = __builtin_amdgcn_exp2f(fmaf(sq, kv[m], kv2[m]));
        float s = (((e[0]+e[1])+(e[2]+e[3])) + ((e[4]+e[5])+(e[6]+e[7])))
                + (((e[8]+e[9])+(e[10]+e[11])) + ((e[12]+e[13])+(e[14]+e[15])));
        float inv = 0.125f * __builtin_amdgcn_rcpf(wave_sum64(s));
        #pragma unroll
        for (int m = 0; m < 16; ++m) acc[m] = fmaf(e[m], inv, acc[m]);
    }

    __syncthreads();   // all waves done reading kp from s_buf

    // stash P row w as bf16: hi -> row w, lo -> row w+8; XOR-swizzle j ^ (w<<3)
    unsigned short* ps = (unsigned short*)s_buf;
    int swz = w << 3;
    #pragma unroll
    for (int m = 0; m < 16; ++m) {
        int j = m * 64 + lane;
        unsigned short hi = f2bf(acc[m]);
        ps[w * 1024 + (j ^ swz)]       = hi;
        ps[(w + 8) * 1024 + (j ^ swz)] = f2bf(acc[m] - bf2f(hi));
    }
    __syncthreads();

    // attn stores: fire-and-forget, drain under phase-2 compute.
    float* aR = attn + ((size_t)(bh * 1024 + r)) * 1024 + lane;
    #pragma unroll
    for (int m = 0; m < 16; ++m) __builtin_nontemporal_store(acc[m], aR + m * 64);

    // Phase 2: wave w -> cols n0..n0+15, K-half kh; pairs (w, w+4) combine via LDS.
    int n0 = (w & 3) * 16;
    int kh = w >> 2;
    int ar  = lane & 15;
    int asw = (ar & 7) << 3;
    int ak  = (lane >> 4) * 8;
    const unsigned short* ap = ps + ar * 1024;
    size_t boff = (size_t)bh * 65536 + (size_t)(n0 + (lane & 15)) * 1024 + ak;
    const unsigned short* bh_p = vThi + boff;
    const unsigned short* bl_p = vTlo + boff;
    fvec4 c2 = {0.f, 0.f, 0.f, 0.f};
    #pragma unroll 4
    for (int s = kh * 16; s < kh * 16 + 16; ++s) {
        bfrag8 a  = *(const bfrag8*)(ap + ((s * 32 + ak) ^ asw));
        bfrag8 vh = *(const bfrag8*)(bh_p + s * 32);
        bfrag8 vl = *(const bfrag8*)(bl_p + s * 32);
        c2 = __builtin_amdgcn_mfma_f32_16x16x32_bf16(a, vh, c2, 0, 0, 0);
        c2 = __builtin_amdgcn_mfma_f32_16x16x32_bf16(a, vl, c2, 0, 0, 0);
    }
    if (w >= 4) {
        #pragma unroll
        for (int q = 0; q < 4; ++q) sc[(w - 4) * 256 + lane * 4 + q] = c2[q];
    }
    __syncthreads();
    if (w < 4) {
        int b = bh >> 3, h = bh & 7;
        #pragma unroll
        for (int q = 0; q < 4; ++q) {
            float t = c2[q] + sc[w * 256 + lane * 4 + q];
            t += __shfl_xor(t, 32);               // hi row + lo row
            if (lane < 32) {
                int row = rowbase + (lane >> 4) * 4 + q;
                oh[(b * 1024 + row) * 512 + h * 64 + n0 + (lane & 15)] = t;
            }
        }
    }
}

// ---------------- K_G: out = oh @ W_out + b_out --------------------------------------
// 1024 blocks = 256 row-tiles x 4 col-slices (128 cols); 256 thr = 128 cols x 2 K-halves.
__global__ __launch_bounds__(256) void k_out(const float* __restrict__ oh,
                                             const float* __restrict__ Wout,
                                             const float* __restrict__ bout,
                                             float* __restrict__ out) {
    __shared__ float xs[8 * 512];            // 16 KB
    __shared__ float comb[2][128][8];        // 8 KB
    int tid = threadIdx.x;
    int blk = blockIdx.x;                    // 1024
    int cs = blk & 3;
    int i0 = (blk >> 2) * 8;
    const float4* xg = (const float4*)(oh + i0 * 512);
    float4* xs4 = (float4*)xs;
    #pragma unroll
    for (int j = 0; j < 4; ++j) xs4[j * 256 + tid] = xg[j * 256 + tid];
    __syncthreads();

    int t  = tid & 127;
    int kh = tid >> 7;
    int col = cs * 128 + t;
    const float* wp = Wout + col;
    float a[8];
    #pragma unroll
    for (int r = 0; r < 8; ++r) a[r] = 0.f;
    int c4b = kh * 64;
    for (int c4 = c4b; c4 < c4b + 64; ++c4) {
        float w0 = wp[(c4 * 4 + 0) * 512];
        float w1 = wp[(c4 * 4 + 1) * 512];
        float w2 = wp[(c4 * 4 + 2) * 512];
        float w3 = wp[(c4 * 4 + 3) * 512];
        #pragma unroll
        for (int r = 0; r < 8; ++r) {
            float4 xv = *(const float4*)(xs + r * 512 + c4 * 4);
            a[r] = fmaf(xv.x, w0, fmaf(xv.y, w1, fmaf(xv.z, w2, fmaf(xv.w, w3, a[r]))));
        }
    }
    #pragma unroll
    for (int r = 0; r < 8; ++r) comb[kh][t][r] = a[r];
    __syncthreads();

    if (tid < 128) {
        int col2 = cs * 128 + tid;
        float bias = bout[col2];
        #pragma unroll
        for (int r = 0; r < 8; ++r)
            out[(i0 + r) * 512 + col2] = comb[0][tid][r] + comb[1][tid][r] + bias;
    }
}

extern "C" void kernel_launch(void* const* d_in, const int* in_sizes, int n_in,
                              void* d_out, int out_size, void* d_ws, size_t ws_size,
                              hipStream_t stream) {
    const float* x     = (const float*)d_in[0];
    const float* Wqkv  = (const float*)d_in[1];
    const float* theta = (const float*)d_in[2];
    const float* Wout  = (const float*)d_in[3];
    const float* bout  = (const float*)d_in[4];

    float* out  = (float*)d_out;                  // [2,1024,512]
    float* attn = out + 2 * 1024 * 512;           // [2,8,1024,1024]

    float* ws  = (float*)d_ws;
    float* Wqp = ws;                               // 32768
    float* Wkp = ws + 32768;                       // 32768
    float* qp  = ws + 65536;                       // 131072
    float* kp  = ws + 196608;                      // 131072
    unsigned short* vThi = (unsigned short*)(ws + 327680);   // 1,048,576 u16
    unsigned short* vTlo = (unsigned short*)(ws + 851968);   // 1,048,576 u16
    float* oh   = ws + 1376256;                    // 1048576
    float* Wv   = ws + 2424832;                    // 262144

    k_wproj   <<<128,  256, 0, stream>>>(Wqkv, theta, Wqp, Wkp, Wv);
    k_qkp     <<<512,  512, 0, stream>>>(x, Wqp, Wkp, qp, kp);
    k_vproj   <<<1024, 256, 0, stream>>>(x, Wv, vThi, vTlo);
    k_attn_pv <<<2048, 512, 0, stream>>>(qp, kp, vThi, vTlo, attn, oh);
    k_out     <<<1024, 256, 0, stream>>>(oh, Wout, bout, out);
}